// Round 17
// baseline (374.929 us; speedup 1.0000x reference)
//
#include <hip/hip_runtime.h>
#include <hip/hip_bf16.h>
#include <stdint.h>

typedef __bf16 bf16;
typedef bf16 bf16x8 __attribute__((ext_vector_type(8)));
typedef bf16 bf16x4 __attribute__((ext_vector_type(4)));
typedef float f32x4 __attribute__((ext_vector_type(4)));

#define DEV static __device__ __forceinline__

constexpr int Bc = 16, Tc = 1029, Cc = 1024, Hc = 16, Dc = 64;
constexpr int KPAD = 1088;     // 17 * 64  (K/V padded length)
constexpr int QPAD = 1152;     // 9 * 128  (Q padded length)
constexpr int MPAD = 16512;    // 129 * 128
constexpr int MREAL = Bc * Tc; // 16464
constexpr int NBM  = MPAD / 128;  // 129 m-blocks
constexpr int NKT  = KPAD / 64;   // 17
constexpr int NVT  = KPAD / 32;   // 34
constexpr int NPOS = 1024;        // rope table rows
constexpr int CAST_BLKS = MPAD * 1024 / 2048;   // 8256
constexpr int TR0_BLKS  = 96 * 32;              // 3072
constexpr int TR1_BLKS  = 32 * 32;              // 1024
constexpr int CS_BLKS   = NPOS * 64 / 256;      // 256 (cos) + 256 (sin)

DEV void gload16(void* lds_dst, const void* gsrc) {
  __builtin_amdgcn_global_load_lds(
      (const __attribute__((address_space(1))) void*)gsrc,
      (__attribute__((address_space(3))) void*)lds_dst, 16, 0, 0);
}

// m-major XCD decode (nwg % 8 == 0): each XCD owns a contiguous range of
// m-panels (large streamed operand A fetched once chip-wide); small B
// re-fetched per XCD (cheap). n-major form (R14) regressed.
DEV void xcd_decode_m(int bid, int nwg, int nbn, int& bm, int& bn) {
  const int per = nwg >> 3;
  const int idx = (bid & 7) * per + (bid >> 3);
  bm = idx / nbn;
  bn = idx - bm * nbn;
}

// ------ fused prep: cast x -> bf16 + both weight transposes + rope repack
// cs4/sn4[p*64 + c*4 + j] = cosT/sinT[p*64 + j*16 + c]  (j innermost so the
// gemm_qkv epilogue loads one float4 per row instead of 4 scalars).
__global__ __launch_bounds__(256) void prep(const float* __restrict__ x,
                                            bf16* __restrict__ xb,
                                            const float* __restrict__ W0,
                                            bf16* __restrict__ T0,
                                            const float* __restrict__ W1,
                                            bf16* __restrict__ T1,
                                            const float* __restrict__ cosT,
                                            const float* __restrict__ sinT,
                                            float* __restrict__ cs4,
                                            float* __restrict__ sn4) {
  __shared__ float tile[32][33];
  const int bid = blockIdx.x;
  if (bid < CAST_BLKS) {
    const size_t i = ((size_t)bid * 256 + threadIdx.x) * 8;
    const int row = (int)(i >> 10);
    bf16x8 o = {};
    if (row < MREAL) {
      const float4* p = (const float4*)(x + i);
      float4 a = p[0], b = p[1];
      o[0] = (bf16)a.x; o[1] = (bf16)a.y; o[2] = (bf16)a.z; o[3] = (bf16)a.w;
      o[4] = (bf16)b.x; o[5] = (bf16)b.y; o[6] = (bf16)b.z; o[7] = (bf16)b.w;
    }
    *(bf16x8*)(xb + i) = o;
    return;
  }
  int tb = bid - CAST_BLKS;
  if (tb >= TR0_BLKS + TR1_BLKS) {
    // rope table repack: 2*CS_BLKS blocks
    tb -= TR0_BLKS + TR1_BLKS;
    const float* src; float* dst;
    if (tb < CS_BLKS) { src = cosT; dst = cs4; }
    else { tb -= CS_BLKS; src = sinT; dst = sn4; }
    const int e = tb * 256 + threadIdx.x;   // output element index
    const int p = e >> 6;
    const int col = e & 63;
    const int cc = col >> 2;    // c
    const int j = col & 3;
    dst[e] = src[p * 64 + j * 16 + cc];
    return;
  }
  const float* W; bf16* Wt; int cols, bx, by;
  if (tb < TR0_BLKS) { W = W0; Wt = T0; cols = 3072; bx = tb % 96; by = tb / 96; }
  else { tb -= TR0_BLKS; W = W1; Wt = T1; cols = 1024; bx = tb % 32; by = tb / 32; }
  const int rows = 1024;
  const int c0 = bx * 32;
  const int r0 = by * 32;
  const int tr = threadIdx.x >> 5;   // 0..7
  const int tc = threadIdx.x & 31;   // 0..31
#pragma unroll
  for (int j = 0; j < 4; ++j)
    tile[tr + j * 8][tc] = W[(size_t)(r0 + tr + j * 8) * cols + c0 + tc];
  __syncthreads();
#pragma unroll
  for (int j = 0; j < 4; ++j)
    Wt[(size_t)(c0 + tr + j * 8) * rows + r0 + tc] = (bf16)tile[tc][tr + j * 8];
}

// ---------------- QKV GEMM with fused bias + RoPE + head-reshape ----------
// 128x128/BK=32 2-buffer loop; 1D grid + m-major XCD affinity. Epilogue:
// wave's 64-col slab = one head (n_base = n0 + wn; wn pre-scaled). RoPE pair
// d <-> d^32 is register j <-> j^2; cos/sin via packed cs4/sn4 float4 loads.
// Q scaled by log2e/8 (attn uses exp2).
__global__ __launch_bounds__(256) void gemm_qkv(const bf16* __restrict__ A,
                                                const bf16* __restrict__ Bt,
                                                const float* __restrict__ bias,
                                                const float* __restrict__ cs4,
                                                const float* __restrict__ sn4,
                                                const int* __restrict__ npfx_p,
                                                bf16* __restrict__ Qh,
                                                bf16* __restrict__ Kh,
                                                bf16* __restrict__ Vh) {
  constexpr int BM = 128, BN = 128, BK = 32, K = 1024;
  __shared__ bf16 As[2][BM * BK];
  __shared__ bf16 Bs[2][BN * BK];
  const int tid  = threadIdx.x;
  const int lane = tid & 63;
  const int wave = tid >> 6;
  const int g = lane >> 4;
  const int c = lane & 15;
  int bm, bn;
  xcd_decode_m(blockIdx.x, gridDim.x, 24, bm, bn);
  const int m0 = bm * BM;
  const int n0 = bn * BN;
  const int wm = (wave >> 1) * 64;
  const int wn = (wave & 1) * 64;

  auto stage = [&](int buf, int k0) {
#pragma unroll
    for (int j = 0; j < 2; ++j) {
      int idx = j * 256 + tid;
      int row = idx >> 2, ch = idx & 3;
      int sc = ((ch ^ ((row >> 1) & 3)) << 4);
      gload16((char*)&As[buf][0] + idx * 16,
              (const char*)(A + (size_t)(m0 + row) * K + k0) + sc);
    }
#pragma unroll
    for (int j = 0; j < 2; ++j) {
      int idx = j * 256 + tid;
      int row = idx >> 2, ch = idx & 3;
      int sc = ((ch ^ ((row >> 1) & 3)) << 4);
      gload16((char*)&Bs[buf][0] + idx * 16,
              (const char*)(Bt + (size_t)(n0 + row) * K + k0) + sc);
    }
  };

  f32x4 acc[4][4] = {};
  stage(0, 0);
  __syncthreads();
  const int nk = K / BK;
  for (int kt = 0; kt < nk; ++kt) {
    const int buf = kt & 1;
    if (kt + 1 < nk) stage(buf ^ 1, (kt + 1) * BK);
    bf16x8 af[4], bfr[4];
#pragma unroll
    for (int i = 0; i < 4; ++i) {
      const int ra = wm + i * 16 + c;
      const int rb = wn + i * 16 + c;
      af[i]  = *(const bf16x8*)((const char*)&As[buf][0] + ra * 64 +
                                (((g ^ ((ra >> 1) & 3)) << 4)));
      bfr[i] = *(const bf16x8*)((const char*)&Bs[buf][0] + rb * 64 +
                                (((g ^ ((rb >> 1) & 3)) << 4)));
    }
#pragma unroll
    for (int i = 0; i < 4; ++i)
#pragma unroll
      for (int j = 0; j < 4; ++j)
        acc[i][j] = __builtin_amdgcn_mfma_f32_16x16x32_bf16(af[i], bfr[j], acc[i][j], 0, 0, 0);
    __syncthreads();
  }

  // ---- fused epilogue ----
  const int npfx = *npfx_p;
  const int n_base = n0 + wn;             // wn already *64 -> one head slab
  const int region = n_base >> 10;        // 0=Q, 1=K, 2=V (wave-uniform)
  const int h = (n_base & 1023) >> 6;
  float bv[4];
#pragma unroll
  for (int j = 0; j < 4; ++j) bv[j] = bias[n_base + j * 16 + c];

#pragma unroll
  for (int i = 0; i < 4; ++i) {
    const int mb = m0 + wm + i * 16 + g * 4;
#pragma unroll
    for (int r = 0; r < 4; ++r) {
      const int m = mb + r;
      if (m >= MREAL) continue;
      const int b = m / Tc;
      const int t = m - b * Tc;
      float val[4];
#pragma unroll
      for (int j = 0; j < 4; ++j) val[j] = acc[i][j][r] + bv[j];
      const int bh = b * Hc + h;
      if (region == 2) {
        bf16* dst = Vh + (((size_t)bh * Tc + t) * 64);
#pragma unroll
        for (int j = 0; j < 4; ++j) dst[j * 16 + c] = (bf16)val[j];
      } else {
        float out[4];
        if (t >= npfx) {
          const int p = t - npfx;
          const float4 csv = *(const float4*)(cs4 + p * 64 + c * 4);
          const float4 snv = *(const float4*)(sn4 + p * 64 + c * 4);
          const float cs[4] = {csv.x, csv.y, csv.z, csv.w};
          const float sn[4] = {snv.x, snv.y, snv.z, snv.w};
#pragma unroll
          for (int j = 0; j < 4; ++j) {
            const float sgn = (j < 2) ? -1.f : 1.f;
            out[j] = val[j] * cs[j] + sgn * val[j ^ 2] * sn[j];
          }
        } else {
#pragma unroll
          for (int j = 0; j < 4; ++j) out[j] = val[j];
        }
        if (region == 0) {
          bf16* dst = Qh + (((size_t)bh * QPAD + t) * 64);
#pragma unroll
          for (int j = 0; j < 4; ++j)
            dst[j * 16 + c] = (bf16)(out[j] * 0.18033688f);  // 1/8 * log2(e)
        } else {
          bf16* dst = Kh + (((size_t)bh * KPAD + t) * 64);
#pragma unroll
          for (int j = 0; j < 4; ++j) dst[j * 16 + c] = (bf16)out[j];
        }
      }
    }
  }
}

// ---------------- GEMM: C = A @ Bt^T + bias (output projection, f32 out) ----
// 1D grid + m-major XCD affinity.
__global__ __launch_bounds__(256) void gemm_out(const bf16* __restrict__ A,
                                                const bf16* __restrict__ Bt,
                                                const float* __restrict__ bias,
                                                float* __restrict__ Cout,
                                                int N, int K, int Mlim) {
  constexpr int BM = 128, BN = 128, BK = 32;
  __shared__ bf16 As[2][BM * BK];
  __shared__ bf16 Bs[2][BN * BK];
  const int tid  = threadIdx.x;
  const int lane = tid & 63;
  const int wave = tid >> 6;
  const int g = lane >> 4;
  const int c = lane & 15;
  int bm, bn;
  xcd_decode_m(blockIdx.x, gridDim.x, 8, bm, bn);
  const int m0 = bm * BM;
  const int n0 = bn * BN;
  const int wm = (wave >> 1) * 64;
  const int wn = (wave & 1) * 64;

  auto stage = [&](int buf, int k0) {
#pragma unroll
    for (int j = 0; j < 2; ++j) {
      int idx = j * 256 + tid;
      int row = idx >> 2, ch = idx & 3;
      int sc = ((ch ^ ((row >> 1) & 3)) << 4);
      gload16((char*)&As[buf][0] + idx * 16,
              (const char*)(A + (size_t)(m0 + row) * K + k0) + sc);
    }
#pragma unroll
    for (int j = 0; j < 2; ++j) {
      int idx = j * 256 + tid;
      int row = idx >> 2, ch = idx & 3;
      int sc = ((ch ^ ((row >> 1) & 3)) << 4);
      gload16((char*)&Bs[buf][0] + idx * 16,
              (const char*)(Bt + (size_t)(n0 + row) * K + k0) + sc);
    }
  };

  f32x4 acc[4][4] = {};
  stage(0, 0);
  __syncthreads();
  const int nk = K / BK;
  for (int kt = 0; kt < nk; ++kt) {
    const int buf = kt & 1;
    if (kt + 1 < nk) stage(buf ^ 1, (kt + 1) * BK);
    bf16x8 af[4], bfr[4];
#pragma unroll
    for (int i = 0; i < 4; ++i) {
      const int ra = wm + i * 16 + c;
      const int rb = wn + i * 16 + c;
      af[i]  = *(const bf16x8*)((const char*)&As[buf][0] + ra * 64 +
                                (((g ^ ((ra >> 1) & 3)) << 4)));
      bfr[i] = *(const bf16x8*)((const char*)&Bs[buf][0] + rb * 64 +
                                (((g ^ ((rb >> 1) & 3)) << 4)));
    }
#pragma unroll
    for (int i = 0; i < 4; ++i)
#pragma unroll
      for (int j = 0; j < 4; ++j)
        acc[i][j] = __builtin_amdgcn_mfma_f32_16x16x32_bf16(af[i], bfr[j], acc[i][j], 0, 0, 0);
    __syncthreads();
  }

#pragma unroll
  for (int i = 0; i < 4; ++i) {
    const int mb = m0 + wm + i * 16 + g * 4;
#pragma unroll
    for (int j = 0; j < 4; ++j) {
      const int n = n0 + wn + j * 16 + c;
      const float bv = bias[n];
#pragma unroll
      for (int r = 0; r < 4; ++r) {
        const int m = mb + r;
        if (m < Mlim) Cout[(size_t)m * N + n] = acc[i][j][r] + bv;
      }
    }
  }
}

// ---------------- V transpose: Vh [bh][Tc][64] -> Vt [bh][64][KPAD] --------
__global__ __launch_bounds__(256) void vtrans2(const bf16* __restrict__ Vh,
                                               bf16* __restrict__ Vt) {
  __shared__ bf16 lds[64][40];
  const int blk = blockIdx.x;
  const int tt = blk % NVT;
  const int bh = blk / NVT;
  const int t0 = tt * 32;
  const int tl = threadIdx.x >> 3;  // 0..31
  const int ch = threadIdx.x & 7;   // 0..7
  bf16x8 v = {};
  const int t = t0 + tl;
  if (t < Tc)
    v = *(const bf16x8*)(Vh + ((size_t)bh * Tc + t) * 64 + ch * 8);
#pragma unroll
  for (int u = 0; u < 8; ++u) lds[ch * 8 + u][tl] = v[u];
  __syncthreads();
  const int d  = threadIdx.x >> 2;  // 0..63
  const int tc = threadIdx.x & 3;   // 0..3
  bf16x8 o = *(const bf16x8*)&lds[d][tc * 8];
  *(bf16x8*)(Vt + ((size_t)bh * Dc + d) * KPAD + t0 + tc * 8) = o;
}

// ---------------- flash attention v4 + XCD-affinity block swizzle ----------
// Waves whose whole 32-row q-tile is padding (q0 >= Tc) skip compute but keep
// staging + barriers (wave-uniform guard; sync structure untouched).
__global__ __launch_bounds__(256, 3) void attn4(const bf16* __restrict__ Qh,
                                                const bf16* __restrict__ Kh,
                                                const bf16* __restrict__ Vt,
                                                bf16* __restrict__ y2d) {
  __shared__ bf16 Ks[2][64 * 64];   // [kv token][d], XOR-swizzled rows (128B)
  __shared__ bf16 Vs[2][64 * 64];   // [d][kv], XOR-swizzled rows
  __shared__ bf16 Ps[4][32 * 64];   // per-wave P [q][k], swizzled
  const int orig = blockIdx.x;
  const int swz = (orig & 7) * 288 + (orig >> 3);   // bijective (2304 = 8*288)
  const int bh = swz / 9;
  const int qt = swz % 9;
  const int b = bh >> 4, h = bh & 15;
  const int tid = threadIdx.x;
  const int w = tid >> 6, lane = tid & 63;
  const int g = lane >> 4, c = lane & 15;
  const int q0 = qt * 128 + w * 32;
  const bool active = (q0 < Tc);
  const bf16* Qb = Qh + (size_t)bh * QPAD * Dc;
  const bf16* Kb = Kh + (size_t)bh * KPAD * Dc;
  const bf16* Vb = Vt + (size_t)bh * Dc * KPAD;
  char* Pw = (char*)&Ps[w][0];

  auto stage = [&](int buf, int k0) {
#pragma unroll
    for (int j = 0; j < 2; ++j) {
      int idx = j * 256 + tid;            // 512 x 16B = 8KB
      int row = idx >> 3;
      int scb = ((idx & 7) << 4) ^ ((row & 7) << 4);
      gload16((char*)&Ks[buf][0] + idx * 16,
              (const char*)(Kb + (size_t)(k0 + row) * 64) + scb);
    }
#pragma unroll
    for (int j = 0; j < 2; ++j) {
      int idx = j * 256 + tid;
      int row = idx >> 3;
      int scb = ((idx & 7) << 4) ^ ((row & 7) << 4);
      gload16((char*)&Vs[buf][0] + idx * 16,
              (const char*)(Vb + (size_t)row * KPAD + k0) + scb);
    }
  };

  // Q fragments (B-operand: col = c)
  bf16x8 qf[2][2];
  if (active) {
#pragma unroll
    for (int fm = 0; fm < 2; ++fm)
#pragma unroll
      for (int kc = 0; kc < 2; ++kc)
        qf[fm][kc] = *(const bf16x8*)(Qb + (size_t)(q0 + fm * 16 + c) * Dc + kc * 32 + g * 8);
  }

  bf16x8 ones;
#pragma unroll
  for (int u = 0; u < 8; ++u) ones[u] = (bf16)1.0f;

  float mrun[2] = {-1e30f, -1e30f}, lrun[2] = {0.f, 0.f};
  f32x4 oacc[2][4] = {};   // [fm(q tile)][fd(d tile)]: q=fm*16+c, d=fd*16+g*4+r

  stage(0, 0);
  __syncthreads();

  for (int kt = 0; kt < NKT; ++kt) {
    const int buf = kt & 1;
    const int k0 = kt * 64;
    if (kt + 1 < NKT) stage(buf ^ 1, (kt + 1) * 64);

    if (active) {
      // --- S^T[k][q] = mfma(K-frag, Q-frag): q=fm*16+c, k=fn*16+g*4+r ---
      f32x4 st[4][2] = {};
      __builtin_amdgcn_s_setprio(1);
#pragma unroll
      for (int fn = 0; fn < 4; ++fn) {
        const int row = fn * 16 + c;
        const int sw = (row & 7) << 4;
#pragma unroll
        for (int kc = 0; kc < 2; ++kc) {
          bf16x8 kf = *(const bf16x8*)((const char*)&Ks[buf][0] + row * 128 +
                                       ((kc * 64 + g * 16) ^ sw));
#pragma unroll
          for (int fm = 0; fm < 2; ++fm)
            st[fn][fm] = __builtin_amdgcn_mfma_f32_16x16x32_bf16(kf, qf[fm][kc], st[fn][fm], 0, 0, 0);
        }
      }
      __builtin_amdgcn_s_setprio(0);

      // --- tail mask (k lane-local: fn*16+g*4+r) ---
      if (k0 + 64 > Tc) {
#pragma unroll
        for (int fn = 0; fn < 4; ++fn)
#pragma unroll
          for (int r = 0; r < 4; ++r)
            if (k0 + fn * 16 + g * 4 + r >= Tc) {
              st[fn][0][r] = -1e30f;
              st[fn][1][r] = -1e30f;
            }
      }

      // --- softmax: local max + 2 shfl; exp2; packed P store ---
      float mx[2];
#pragma unroll
      for (int fm = 0; fm < 2; ++fm) {
        float m0_ = fmaxf(fmaxf(st[0][fm][0], st[0][fm][1]), fmaxf(st[0][fm][2], st[0][fm][3]));
        float m1_ = fmaxf(fmaxf(st[1][fm][0], st[1][fm][1]), fmaxf(st[1][fm][2], st[1][fm][3]));
        float m2_ = fmaxf(fmaxf(st[2][fm][0], st[2][fm][1]), fmaxf(st[2][fm][2], st[2][fm][3]));
        float m3_ = fmaxf(fmaxf(st[3][fm][0], st[3][fm][1]), fmaxf(st[3][fm][2], st[3][fm][3]));
        float m = fmaxf(fmaxf(m0_, m1_), fmaxf(m2_, m3_));
        m = fmaxf(m, __shfl_xor(m, 16));
        m = fmaxf(m, __shfl_xor(m, 32));
        mx[fm] = m;
      }
      const bool ok = (mx[0] - mrun[0] <= 11.f) && (mx[1] - mrun[1] <= 11.f);
      if (!__all(ok)) {
#pragma unroll
        for (int fm = 0; fm < 2; ++fm) {
          const float mnew = fmaxf(mrun[fm], mx[fm]);
          const float al = __builtin_amdgcn_exp2f(mrun[fm] - mnew);
          mrun[fm] = mnew;
          lrun[fm] *= al;
#pragma unroll
          for (int fd = 0; fd < 4; ++fd) oacc[fm][fd] *= al;
        }
      }
#pragma unroll
      for (int fm = 0; fm < 2; ++fm) {
        const int row = fm * 16 + c;
        const int sw = (row & 7) << 4;
#pragma unroll
        for (int fn = 0; fn < 4; ++fn) {
          bf16x4 pv;
#pragma unroll
          for (int r = 0; r < 4; ++r)
            pv[r] = (bf16)__builtin_amdgcn_exp2f(st[fn][fm][r] - mrun[fm]);
          *(bf16x4*)(Pw + row * 128 + ((fn * 32 + g * 8) ^ sw)) = pv;
        }
      }

      // --- P^T fragments + row-sum + PV (O^T) ---
      bf16x8 pf[2][2];
      f32x4 ps2[2] = {};
#pragma unroll
      for (int fm = 0; fm < 2; ++fm) {
        const int row = fm * 16 + c;
        const int sw = (row & 7) << 4;
#pragma unroll
        for (int kc = 0; kc < 2; ++kc) {
          pf[fm][kc] = *(const bf16x8*)(Pw + row * 128 + ((kc * 64 + g * 16) ^ sw));
          ps2[fm] = __builtin_amdgcn_mfma_f32_16x16x32_bf16(ones, pf[fm][kc], ps2[fm], 0, 0, 0);
        }
      }
      __builtin_amdgcn_s_setprio(1);
#pragma unroll
      for (int fd = 0; fd < 4; ++fd) {
        const int row = fd * 16 + c;
        const int sw = (row & 7) << 4;
#pragma unroll
        for (int kc = 0; kc < 2; ++kc) {
          bf16x8 vf = *(const bf16x8*)((const char*)&Vs[buf][0] + row * 128 +
                                       ((kc * 64 + g * 16) ^ sw));
#pragma unroll
          for (int fm = 0; fm < 2; ++fm)
            oacc[fm][fd] = __builtin_amdgcn_mfma_f32_16x16x32_bf16(vf, pf[fm][kc], oacc[fm][fd], 0, 0, 0);
        }
      }
      __builtin_amdgcn_s_setprio(0);
#pragma unroll
      for (int fm = 0; fm < 2; ++fm) lrun[fm] += ps2[fm][0];
    }
    __syncthreads();
  }

  // --- epilogue: lane (g,c) owns q=fm*16+c, d=fd*16+g*4+r -> 8B packed stores
  if (active) {
#pragma unroll
    for (int fm = 0; fm < 2; ++fm) {
      const int trow = q0 + fm * 16 + c;
      if (trow < Tc) {
        const float inv = 1.f / lrun[fm];
#pragma unroll
        for (int fd = 0; fd < 4; ++fd) {
          bf16x4 ov;
#pragma unroll
          for (int r = 0; r < 4; ++r) ov[r] = (bf16)(oacc[fm][fd][r] * inv);
          *(bf16x4*)(y2d + ((size_t)b * Tc + trow) * Cc + h * Dc + fd * 16 + g * 4) = ov;
        }
      }
    }
  }
}

// ---------------- launch ----------------
extern "C" void kernel_launch(void* const* d_in, const int* in_sizes, int n_in,
                              void* d_out, int out_size, void* d_ws, size_t ws_size,
                              hipStream_t stream) {
  const float* x    = (const float*)d_in[0];
  const float* Wqkv = (const float*)d_in[1];
  const float* bqkv = (const float*)d_in[2];
  const float* Wout = (const float*)d_in[3];
  const float* bout = (const float*)d_in[4];
  const float* cosT = (const float*)d_in[5];
  const float* sinT = (const float*)d_in[6];
  const int*   npfx = (const int*)d_in[7];

  char* ws = (char*)d_ws;
  size_t off = 0;
  auto alloc = [&](size_t bytes) {
    char* p = ws + off;
    off = (off + bytes + 255) & ~(size_t)255;
    return p;
  };
  bf16*  xb  = (bf16*)alloc((size_t)MPAD * 1024 * 2);   // also reused as y2d
  bf16*  Wt1 = (bf16*)alloc((size_t)3072 * 1024 * 2);
  bf16*  Wt2 = (bf16*)alloc((size_t)1024 * 1024 * 2);
  bf16*  Qh  = (bf16*)alloc((size_t)256 * QPAD * 64 * 2);
  bf16*  Kh  = (bf16*)alloc((size_t)256 * KPAD * 64 * 2);
  bf16*  Vh  = (bf16*)alloc((size_t)256 * Tc * 64 * 2);
  bf16*  Vt  = (bf16*)alloc((size_t)256 * KPAD * 64 * 2);
  float* cs4 = (float*)alloc((size_t)NPOS * 64 * 4);
  float* sn4 = (float*)alloc((size_t)NPOS * 64 * 4);
  bf16*  y2d = xb;
  if (off > ws_size) return;

  prep<<<dim3(CAST_BLKS + TR0_BLKS + TR1_BLKS + 2 * CS_BLKS), dim3(256), 0, stream>>>(
      x, xb, Wqkv, Wt1, Wout, Wt2, cosT, sinT, cs4, sn4);
  gemm_qkv<<<dim3(24 * NBM), dim3(256), 0, stream>>>(
      xb, Wt1, bqkv, cs4, sn4, npfx, Qh, Kh, Vh);
  vtrans2<<<dim3(256 * NVT), dim3(256), 0, stream>>>(Vh, Vt);
  attn4<<<dim3(2304), dim3(256), 0, stream>>>(Qh, Kh, Vt, y2d);
  gemm_out<<<dim3(8 * NBM), dim3(256), 0, stream>>>(
      y2d, Wt2, bout, (float*)d_out, 1024, 1024, MREAL);
}

// Round 18
// 363.252 us; speedup vs baseline: 1.0321x; 1.0321x over previous
//
#include <hip/hip_runtime.h>
#include <hip/hip_bf16.h>
#include <stdint.h>

typedef __bf16 bf16;
typedef bf16 bf16x8 __attribute__((ext_vector_type(8)));
typedef bf16 bf16x4 __attribute__((ext_vector_type(4)));
typedef float f32x4 __attribute__((ext_vector_type(4)));

#define DEV static __device__ __forceinline__

constexpr int Bc = 16, Tc = 1029, Cc = 1024, Hc = 16, Dc = 64;
constexpr int KPAD = 1088;     // 17 * 64  (K/V padded length)
constexpr int QPAD = 1152;     // 9 * 128  (Q padded length)
constexpr int MPAD = 16512;    // 129 * 128
constexpr int MREAL = Bc * Tc; // 16464
constexpr int NBM  = MPAD / 128;  // 129 m-blocks
constexpr int NKT  = KPAD / 64;   // 17
constexpr int NVT  = KPAD / 32;   // 34
constexpr int NPOS = 1024;        // rope table rows
constexpr int CAST_BLKS = MPAD * 1024 / 2048;   // 8256
constexpr int TR0_BLKS  = 96 * 32;              // 3072
constexpr int TR1_BLKS  = 32 * 32;              // 1024
constexpr int CS_BLKS   = NPOS * 64 / 256;      // 256 (cos) + 256 (sin)

DEV void gload16(void* lds_dst, const void* gsrc) {
  __builtin_amdgcn_global_load_lds(
      (const __attribute__((address_space(1))) void*)gsrc,
      (__attribute__((address_space(3))) void*)lds_dst, 16, 0, 0);
}

// m-major XCD decode (nwg % 8 == 0): each XCD owns a contiguous range of
// m-panels (large streamed operand A fetched once chip-wide); small B
// re-fetched per XCD (cheap). n-major form (R14) regressed.
DEV void xcd_decode_m(int bid, int nwg, int nbn, int& bm, int& bn) {
  const int per = nwg >> 3;
  const int idx = (bid & 7) * per + (bid >> 3);
  bm = idx / nbn;
  bn = idx - bm * nbn;
}

// ------ fused prep: cast x -> bf16 + both weight transposes + rope repack
// cs4/sn4[p*64 + c*4 + j] = cosT/sinT[p*64 + j*16 + c]  (j innermost so the
// gemm_qkv epilogue loads one float4 per row instead of 4 scalars).
__global__ __launch_bounds__(256) void prep(const float* __restrict__ x,
                                            bf16* __restrict__ xb,
                                            const float* __restrict__ W0,
                                            bf16* __restrict__ T0,
                                            const float* __restrict__ W1,
                                            bf16* __restrict__ T1,
                                            const float* __restrict__ cosT,
                                            const float* __restrict__ sinT,
                                            float* __restrict__ cs4,
                                            float* __restrict__ sn4) {
  __shared__ float tile[32][33];
  const int bid = blockIdx.x;
  if (bid < CAST_BLKS) {
    const size_t i = ((size_t)bid * 256 + threadIdx.x) * 8;
    const int row = (int)(i >> 10);
    bf16x8 o = {};
    if (row < MREAL) {
      const float4* p = (const float4*)(x + i);
      float4 a = p[0], b = p[1];
      o[0] = (bf16)a.x; o[1] = (bf16)a.y; o[2] = (bf16)a.z; o[3] = (bf16)a.w;
      o[4] = (bf16)b.x; o[5] = (bf16)b.y; o[6] = (bf16)b.z; o[7] = (bf16)b.w;
    }
    *(bf16x8*)(xb + i) = o;
    return;
  }
  int tb = bid - CAST_BLKS;
  if (tb >= TR0_BLKS + TR1_BLKS) {
    // rope table repack: 2*CS_BLKS blocks
    tb -= TR0_BLKS + TR1_BLKS;
    const float* src; float* dst;
    if (tb < CS_BLKS) { src = cosT; dst = cs4; }
    else { tb -= CS_BLKS; src = sinT; dst = sn4; }
    const int e = tb * 256 + threadIdx.x;   // output element index
    const int p = e >> 6;
    const int col = e & 63;
    const int cc = col >> 2;    // c
    const int j = col & 3;
    dst[e] = src[p * 64 + j * 16 + cc];
    return;
  }
  const float* W; bf16* Wt; int cols, bx, by;
  if (tb < TR0_BLKS) { W = W0; Wt = T0; cols = 3072; bx = tb % 96; by = tb / 96; }
  else { tb -= TR0_BLKS; W = W1; Wt = T1; cols = 1024; bx = tb % 32; by = tb / 32; }
  const int rows = 1024;
  const int c0 = bx * 32;
  const int r0 = by * 32;
  const int tr = threadIdx.x >> 5;   // 0..7
  const int tc = threadIdx.x & 31;   // 0..31
#pragma unroll
  for (int j = 0; j < 4; ++j)
    tile[tr + j * 8][tc] = W[(size_t)(r0 + tr + j * 8) * cols + c0 + tc];
  __syncthreads();
#pragma unroll
  for (int j = 0; j < 4; ++j)
    Wt[(size_t)(c0 + tr + j * 8) * rows + r0 + tc] = (bf16)tile[tc][tr + j * 8];
}

// ---------------- QKV GEMM with fused bias + RoPE + head-reshape ----------
// 128x128/BK=32 2-buffer loop; 1D grid + m-major XCD affinity. Epilogue:
// wave's 64-col slab = one head (n_base = n0 + wn; wn pre-scaled). RoPE pair
// d <-> d^32 is register j <-> j^2; cos/sin via packed cs4/sn4 float4 loads.
// Q scaled by log2e/8 (attn uses exp2).
__global__ __launch_bounds__(256) void gemm_qkv(const bf16* __restrict__ A,
                                                const bf16* __restrict__ Bt,
                                                const float* __restrict__ bias,
                                                const float* __restrict__ cs4,
                                                const float* __restrict__ sn4,
                                                const int* __restrict__ npfx_p,
                                                bf16* __restrict__ Qh,
                                                bf16* __restrict__ Kh,
                                                bf16* __restrict__ Vh) {
  constexpr int BM = 128, BN = 128, BK = 32, K = 1024;
  __shared__ bf16 As[2][BM * BK];
  __shared__ bf16 Bs[2][BN * BK];
  const int tid  = threadIdx.x;
  const int lane = tid & 63;
  const int wave = tid >> 6;
  const int g = lane >> 4;
  const int c = lane & 15;
  int bm, bn;
  xcd_decode_m(blockIdx.x, gridDim.x, 24, bm, bn);
  const int m0 = bm * BM;
  const int n0 = bn * BN;
  const int wm = (wave >> 1) * 64;
  const int wn = (wave & 1) * 64;

  auto stage = [&](int buf, int k0) {
#pragma unroll
    for (int j = 0; j < 2; ++j) {
      int idx = j * 256 + tid;
      int row = idx >> 2, ch = idx & 3;
      int sc = ((ch ^ ((row >> 1) & 3)) << 4);
      gload16((char*)&As[buf][0] + idx * 16,
              (const char*)(A + (size_t)(m0 + row) * K + k0) + sc);
    }
#pragma unroll
    for (int j = 0; j < 2; ++j) {
      int idx = j * 256 + tid;
      int row = idx >> 2, ch = idx & 3;
      int sc = ((ch ^ ((row >> 1) & 3)) << 4);
      gload16((char*)&Bs[buf][0] + idx * 16,
              (const char*)(Bt + (size_t)(n0 + row) * K + k0) + sc);
    }
  };

  f32x4 acc[4][4] = {};
  stage(0, 0);
  __syncthreads();
  const int nk = K / BK;
  for (int kt = 0; kt < nk; ++kt) {
    const int buf = kt & 1;
    if (kt + 1 < nk) stage(buf ^ 1, (kt + 1) * BK);
    bf16x8 af[4], bfr[4];
#pragma unroll
    for (int i = 0; i < 4; ++i) {
      const int ra = wm + i * 16 + c;
      const int rb = wn + i * 16 + c;
      af[i]  = *(const bf16x8*)((const char*)&As[buf][0] + ra * 64 +
                                (((g ^ ((ra >> 1) & 3)) << 4)));
      bfr[i] = *(const bf16x8*)((const char*)&Bs[buf][0] + rb * 64 +
                                (((g ^ ((rb >> 1) & 3)) << 4)));
    }
#pragma unroll
    for (int i = 0; i < 4; ++i)
#pragma unroll
      for (int j = 0; j < 4; ++j)
        acc[i][j] = __builtin_amdgcn_mfma_f32_16x16x32_bf16(af[i], bfr[j], acc[i][j], 0, 0, 0);
    __syncthreads();
  }

  // ---- fused epilogue ----
  const int npfx = *npfx_p;
  const int n_base = n0 + wn;             // wn already *64 -> one head slab
  const int region = n_base >> 10;        // 0=Q, 1=K, 2=V (wave-uniform)
  const int h = (n_base & 1023) >> 6;
  float bv[4];
#pragma unroll
  for (int j = 0; j < 4; ++j) bv[j] = bias[n_base + j * 16 + c];

#pragma unroll
  for (int i = 0; i < 4; ++i) {
    const int mb = m0 + wm + i * 16 + g * 4;
#pragma unroll
    for (int r = 0; r < 4; ++r) {
      const int m = mb + r;
      if (m >= MREAL) continue;
      const int b = m / Tc;
      const int t = m - b * Tc;
      float val[4];
#pragma unroll
      for (int j = 0; j < 4; ++j) val[j] = acc[i][j][r] + bv[j];
      const int bh = b * Hc + h;
      if (region == 2) {
        bf16* dst = Vh + (((size_t)bh * Tc + t) * 64);
#pragma unroll
        for (int j = 0; j < 4; ++j) dst[j * 16 + c] = (bf16)val[j];
      } else {
        float out[4];
        if (t >= npfx) {
          const int p = t - npfx;
          const float4 csv = *(const float4*)(cs4 + p * 64 + c * 4);
          const float4 snv = *(const float4*)(sn4 + p * 64 + c * 4);
          const float cs[4] = {csv.x, csv.y, csv.z, csv.w};
          const float sn[4] = {snv.x, snv.y, snv.z, snv.w};
#pragma unroll
          for (int j = 0; j < 4; ++j) {
            const float sgn = (j < 2) ? -1.f : 1.f;
            out[j] = val[j] * cs[j] + sgn * val[j ^ 2] * sn[j];
          }
        } else {
#pragma unroll
          for (int j = 0; j < 4; ++j) out[j] = val[j];
        }
        if (region == 0) {
          bf16* dst = Qh + (((size_t)bh * QPAD + t) * 64);
#pragma unroll
          for (int j = 0; j < 4; ++j)
            dst[j * 16 + c] = (bf16)(out[j] * 0.18033688f);  // 1/8 * log2(e)
        } else {
          bf16* dst = Kh + (((size_t)bh * KPAD + t) * 64);
#pragma unroll
          for (int j = 0; j < 4; ++j) dst[j * 16 + c] = (bf16)out[j];
        }
      }
    }
  }
}

// ---------------- GEMM: C = A @ Bt^T + bias (output projection, f32 out) ----
// 1D grid + m-major XCD affinity.
__global__ __launch_bounds__(256) void gemm_out(const bf16* __restrict__ A,
                                                const bf16* __restrict__ Bt,
                                                const float* __restrict__ bias,
                                                float* __restrict__ Cout,
                                                int N, int K, int Mlim) {
  constexpr int BM = 128, BN = 128, BK = 32;
  __shared__ bf16 As[2][BM * BK];
  __shared__ bf16 Bs[2][BN * BK];
  const int tid  = threadIdx.x;
  const int lane = tid & 63;
  const int wave = tid >> 6;
  const int g = lane >> 4;
  const int c = lane & 15;
  int bm, bn;
  xcd_decode_m(blockIdx.x, gridDim.x, 8, bm, bn);
  const int m0 = bm * BM;
  const int n0 = bn * BN;
  const int wm = (wave >> 1) * 64;
  const int wn = (wave & 1) * 64;

  auto stage = [&](int buf, int k0) {
#pragma unroll
    for (int j = 0; j < 2; ++j) {
      int idx = j * 256 + tid;
      int row = idx >> 2, ch = idx & 3;
      int sc = ((ch ^ ((row >> 1) & 3)) << 4);
      gload16((char*)&As[buf][0] + idx * 16,
              (const char*)(A + (size_t)(m0 + row) * K + k0) + sc);
    }
#pragma unroll
    for (int j = 0; j < 2; ++j) {
      int idx = j * 256 + tid;
      int row = idx >> 2, ch = idx & 3;
      int sc = ((ch ^ ((row >> 1) & 3)) << 4);
      gload16((char*)&Bs[buf][0] + idx * 16,
              (const char*)(Bt + (size_t)(n0 + row) * K + k0) + sc);
    }
  };

  f32x4 acc[4][4] = {};
  stage(0, 0);
  __syncthreads();
  const int nk = K / BK;
  for (int kt = 0; kt < nk; ++kt) {
    const int buf = kt & 1;
    if (kt + 1 < nk) stage(buf ^ 1, (kt + 1) * BK);
    bf16x8 af[4], bfr[4];
#pragma unroll
    for (int i = 0; i < 4; ++i) {
      const int ra = wm + i * 16 + c;
      const int rb = wn + i * 16 + c;
      af[i]  = *(const bf16x8*)((const char*)&As[buf][0] + ra * 64 +
                                (((g ^ ((ra >> 1) & 3)) << 4)));
      bfr[i] = *(const bf16x8*)((const char*)&Bs[buf][0] + rb * 64 +
                                (((g ^ ((rb >> 1) & 3)) << 4)));
    }
#pragma unroll
    for (int i = 0; i < 4; ++i)
#pragma unroll
      for (int j = 0; j < 4; ++j)
        acc[i][j] = __builtin_amdgcn_mfma_f32_16x16x32_bf16(af[i], bfr[j], acc[i][j], 0, 0, 0);
    __syncthreads();
  }

#pragma unroll
  for (int i = 0; i < 4; ++i) {
    const int mb = m0 + wm + i * 16 + g * 4;
#pragma unroll
    for (int j = 0; j < 4; ++j) {
      const int n = n0 + wn + j * 16 + c;
      const float bv = bias[n];
#pragma unroll
      for (int r = 0; r < 4; ++r) {
        const int m = mb + r;
        if (m < Mlim) Cout[(size_t)m * N + n] = acc[i][j][r] + bv;
      }
    }
  }
}

// ---------------- V transpose: Vh [bh][Tc][64] -> Vt [bh][64][KPAD] --------
__global__ __launch_bounds__(256) void vtrans2(const bf16* __restrict__ Vh,
                                               bf16* __restrict__ Vt) {
  __shared__ bf16 lds[64][40];
  const int blk = blockIdx.x;
  const int tt = blk % NVT;
  const int bh = blk / NVT;
  const int t0 = tt * 32;
  const int tl = threadIdx.x >> 3;  // 0..31
  const int ch = threadIdx.x & 7;   // 0..7
  bf16x8 v = {};
  const int t = t0 + tl;
  if (t < Tc)
    v = *(const bf16x8*)(Vh + ((size_t)bh * Tc + t) * 64 + ch * 8);
#pragma unroll
  for (int u = 0; u < 8; ++u) lds[ch * 8 + u][tl] = v[u];
  __syncthreads();
  const int d  = threadIdx.x >> 2;  // 0..63
  const int tc = threadIdx.x & 3;   // 0..3
  bf16x8 o = *(const bf16x8*)&lds[d][tc * 8];
  *(bf16x8*)(Vt + ((size_t)bh * Dc + d) * KPAD + t0 + tc * 8) = o;
}

// ---------------- flash attention v4 + XCD-affinity block swizzle ----------
// Waves whose whole 32-row q-tile is padding (q0 >= Tc) skip compute but keep
// staging + barriers (wave-uniform guard; sync structure untouched).
__global__ __launch_bounds__(256, 3) void attn4(const bf16* __restrict__ Qh,
                                                const bf16* __restrict__ Kh,
                                                const bf16* __restrict__ Vt,
                                                bf16* __restrict__ y2d) {
  __shared__ bf16 Ks[2][64 * 64];   // [kv token][d], XOR-swizzled rows (128B)
  __shared__ bf16 Vs[2][64 * 64];   // [d][kv], XOR-swizzled rows
  __shared__ bf16 Ps[4][32 * 64];   // per-wave P [q][k], swizzled
  const int orig = blockIdx.x;
  const int swz = (orig & 7) * 288 + (orig >> 3);   // bijective (2304 = 8*288)
  const int bh = swz / 9;
  const int qt = swz % 9;
  const int b = bh >> 4, h = bh & 15;
  const int tid = threadIdx.x;
  const int w = tid >> 6, lane = tid & 63;
  const int g = lane >> 4, c = lane & 15;
  const int q0 = qt * 128 + w * 32;
  const bool active = (q0 < Tc);
  const bf16* Qb = Qh + (size_t)bh * QPAD * Dc;
  const bf16* Kb = Kh + (size_t)bh * KPAD * Dc;
  const bf16* Vb = Vt + (size_t)bh * Dc * KPAD;
  char* Pw = (char*)&Ps[w][0];

  auto stage = [&](int buf, int k0) {
#pragma unroll
    for (int j = 0; j < 2; ++j) {
      int idx = j * 256 + tid;            // 512 x 16B = 8KB
      int row = idx >> 3;
      int scb = ((idx & 7) << 4) ^ ((row & 7) << 4);
      gload16((char*)&Ks[buf][0] + idx * 16,
              (const char*)(Kb + (size_t)(k0 + row) * 64) + scb);
    }
#pragma unroll
    for (int j = 0; j < 2; ++j) {
      int idx = j * 256 + tid;
      int row = idx >> 3;
      int scb = ((idx & 7) << 4) ^ ((row & 7) << 4);
      gload16((char*)&Vs[buf][0] + idx * 16,
              (const char*)(Vb + (size_t)row * KPAD + k0) + scb);
    }
  };

  // Q fragments (B-operand: col = c)
  bf16x8 qf[2][2];
  if (active) {
#pragma unroll
    for (int fm = 0; fm < 2; ++fm)
#pragma unroll
      for (int kc = 0; kc < 2; ++kc)
        qf[fm][kc] = *(const bf16x8*)(Qb + (size_t)(q0 + fm * 16 + c) * Dc + kc * 32 + g * 8);
  }

  bf16x8 ones;
#pragma unroll
  for (int u = 0; u < 8; ++u) ones[u] = (bf16)1.0f;

  float mrun[2] = {-1e30f, -1e30f}, lrun[2] = {0.f, 0.f};
  f32x4 oacc[2][4] = {};   // [fm(q tile)][fd(d tile)]: q=fm*16+c, d=fd*16+g*4+r

  stage(0, 0);
  __syncthreads();

  for (int kt = 0; kt < NKT; ++kt) {
    const int buf = kt & 1;
    const int k0 = kt * 64;
    if (kt + 1 < NKT) stage(buf ^ 1, (kt + 1) * 64);

    if (active) {
      // --- S^T[k][q] = mfma(K-frag, Q-frag): q=fm*16+c, k=fn*16+g*4+r ---
      f32x4 st[4][2] = {};
      __builtin_amdgcn_s_setprio(1);
#pragma unroll
      for (int fn = 0; fn < 4; ++fn) {
        const int row = fn * 16 + c;
        const int sw = (row & 7) << 4;
#pragma unroll
        for (int kc = 0; kc < 2; ++kc) {
          bf16x8 kf = *(const bf16x8*)((const char*)&Ks[buf][0] + row * 128 +
                                       ((kc * 64 + g * 16) ^ sw));
#pragma unroll
          for (int fm = 0; fm < 2; ++fm)
            st[fn][fm] = __builtin_amdgcn_mfma_f32_16x16x32_bf16(kf, qf[fm][kc], st[fn][fm], 0, 0, 0);
        }
      }
      __builtin_amdgcn_s_setprio(0);

      // --- tail mask (k lane-local: fn*16+g*4+r) ---
      if (k0 + 64 > Tc) {
#pragma unroll
        for (int fn = 0; fn < 4; ++fn)
#pragma unroll
          for (int r = 0; r < 4; ++r)
            if (k0 + fn * 16 + g * 4 + r >= Tc) {
              st[fn][0][r] = -1e30f;
              st[fn][1][r] = -1e30f;
            }
      }

      // --- softmax: local max + 2 shfl; exp2; packed P store ---
      float mx[2];
#pragma unroll
      for (int fm = 0; fm < 2; ++fm) {
        float m0_ = fmaxf(fmaxf(st[0][fm][0], st[0][fm][1]), fmaxf(st[0][fm][2], st[0][fm][3]));
        float m1_ = fmaxf(fmaxf(st[1][fm][0], st[1][fm][1]), fmaxf(st[1][fm][2], st[1][fm][3]));
        float m2_ = fmaxf(fmaxf(st[2][fm][0], st[2][fm][1]), fmaxf(st[2][fm][2], st[2][fm][3]));
        float m3_ = fmaxf(fmaxf(st[3][fm][0], st[3][fm][1]), fmaxf(st[3][fm][2], st[3][fm][3]));
        float m = fmaxf(fmaxf(m0_, m1_), fmaxf(m2_, m3_));
        m = fmaxf(m, __shfl_xor(m, 16));
        m = fmaxf(m, __shfl_xor(m, 32));
        mx[fm] = m;
      }
      const bool ok = (mx[0] - mrun[0] <= 11.f) && (mx[1] - mrun[1] <= 11.f);
      if (!__all(ok)) {
#pragma unroll
        for (int fm = 0; fm < 2; ++fm) {
          const float mnew = fmaxf(mrun[fm], mx[fm]);
          const float al = __builtin_amdgcn_exp2f(mrun[fm] - mnew);
          mrun[fm] = mnew;
          lrun[fm] *= al;
#pragma unroll
          for (int fd = 0; fd < 4; ++fd) oacc[fm][fd] *= al;
        }
      }
#pragma unroll
      for (int fm = 0; fm < 2; ++fm) {
        const int row = fm * 16 + c;
        const int sw = (row & 7) << 4;
#pragma unroll
        for (int fn = 0; fn < 4; ++fn) {
          bf16x4 pv;
#pragma unroll
          for (int r = 0; r < 4; ++r)
            pv[r] = (bf16)__builtin_amdgcn_exp2f(st[fn][fm][r] - mrun[fm]);
          *(bf16x4*)(Pw + row * 128 + ((fn * 32 + g * 8) ^ sw)) = pv;
        }
      }

      // --- P^T fragments + row-sum + PV (O^T) ---
      bf16x8 pf[2][2];
      f32x4 ps2[2] = {};
#pragma unroll
      for (int fm = 0; fm < 2; ++fm) {
        const int row = fm * 16 + c;
        const int sw = (row & 7) << 4;
#pragma unroll
        for (int kc = 0; kc < 2; ++kc) {
          pf[fm][kc] = *(const bf16x8*)(Pw + row * 128 + ((kc * 64 + g * 16) ^ sw));
          ps2[fm] = __builtin_amdgcn_mfma_f32_16x16x32_bf16(ones, pf[fm][kc], ps2[fm], 0, 0, 0);
        }
      }
      __builtin_amdgcn_s_setprio(1);
#pragma unroll
      for (int fd = 0; fd < 4; ++fd) {
        const int row = fd * 16 + c;
        const int sw = (row & 7) << 4;
#pragma unroll
        for (int kc = 0; kc < 2; ++kc) {
          bf16x8 vf = *(const bf16x8*)((const char*)&Vs[buf][0] + row * 128 +
                                       ((kc * 64 + g * 16) ^ sw));
#pragma unroll
          for (int fm = 0; fm < 2; ++fm)
            oacc[fm][fd] = __builtin_amdgcn_mfma_f32_16x16x32_bf16(vf, pf[fm][kc], oacc[fm][fd], 0, 0, 0);
        }
      }
      __builtin_amdgcn_s_setprio(0);
#pragma unroll
      for (int fm = 0; fm < 2; ++fm) lrun[fm] += ps2[fm][0];
    }
    __syncthreads();
  }

  // --- epilogue: lane (g,c) owns q=fm*16+c, d=fd*16+g*4+r -> 8B packed stores
  if (active) {
#pragma unroll
    for (int fm = 0; fm < 2; ++fm) {
      const int trow = q0 + fm * 16 + c;
      if (trow < Tc) {
        const float inv = 1.f / lrun[fm];
#pragma unroll
        for (int fd = 0; fd < 4; ++fd) {
          bf16x4 ov;
#pragma unroll
          for (int r = 0; r < 4; ++r) ov[r] = (bf16)(oacc[fm][fd][r] * inv);
          *(bf16x4*)(y2d + ((size_t)b * Tc + trow) * Cc + h * Dc + fd * 16 + g * 4) = ov;
        }
      }
    }
  }
}

// ---------------- launch ----------------
extern "C" void kernel_launch(void* const* d_in, const int* in_sizes, int n_in,
                              void* d_out, int out_size, void* d_ws, size_t ws_size,
                              hipStream_t stream) {
  const float* x    = (const float*)d_in[0];
  const float* Wqkv = (const float*)d_in[1];
  const float* bqkv = (const float*)d_in[2];
  const float* Wout = (const float*)d_in[3];
  const float* bout = (const float*)d_in[4];
  const float* cosT = (const float*)d_in[5];
  const float* sinT = (const float*)d_in[6];
  const int*   npfx = (const int*)d_in[7];

  char* ws = (char*)d_ws;
  size_t off = 0;
  auto alloc = [&](size_t bytes) {
    char* p = ws + off;
    off = (off + bytes + 255) & ~(size_t)255;
    return p;
  };
  bf16*  xb  = (bf16*)alloc((size_t)MPAD * 1024 * 2);   // also reused as y2d
  bf16*  Wt1 = (bf16*)alloc((size_t)3072 * 1024 * 2);
  bf16*  Wt2 = (bf16*)alloc((size_t)1024 * 1024 * 2);
  bf16*  Qh  = (bf16*)alloc((size_t)256 * QPAD * 64 * 2);
  bf16*  Kh  = (bf16*)alloc((size_t)256 * KPAD * 64 * 2);
  bf16*  Vh  = (bf16*)alloc((size_t)256 * Tc * 64 * 2);
  bf16*  Vt  = (bf16*)alloc((size_t)256 * KPAD * 64 * 2);
  float* cs4 = (float*)alloc((size_t)NPOS * 64 * 4);
  float* sn4 = (float*)alloc((size_t)NPOS * 64 * 4);
  bf16*  y2d = xb;
  if (off > ws_size) return;

  prep<<<dim3(CAST_BLKS + TR0_BLKS + TR1_BLKS + 2 * CS_BLKS), dim3(256), 0, stream>>>(
      x, xb, Wqkv, Wt1, Wout, Wt2, cosT, sinT, cs4, sn4);
  gemm_qkv<<<dim3(24 * NBM), dim3(256), 0, stream>>>(
      xb, Wt1, bqkv, cs4, sn4, npfx, Qh, Kh, Vh);
  vtrans2<<<dim3(256 * NVT), dim3(256), 0, stream>>>(Vh, Vt);
  attn4<<<dim3(2304), dim3(256), 0, stream>>>(Qh, Kh, Vt, y2d);
  gemm_out<<<dim3(8 * NBM), dim3(256), 0, stream>>>(
      y2d, Wt2, bout, (float*)d_out, 1024, 1024, MREAL);
}